// Round 1
// baseline (261.927 us; speedup 1.0000x reference)
//
#include <hip/hip_runtime.h>
#include <hip/hip_bf16.h>
#include <stdint.h>

// ---------------------------------------------------------------------------
// RelativeCrossAttention: B=4, SQ=SKV=1024, D=1024, H=16, HD=64, MAXL=1024
// Round 1: bf16-MFMA baseline. Pre-convert fp32->bf16 (+weight transpose),
// 4x NT GEMM (128x128 tile, reg-staged LDS), flash-attention with rel-bias
// band-GEMM (T = Q @ rel_band^T, gather T[i][i-j+63]).
// ---------------------------------------------------------------------------

typedef __attribute__((ext_vector_type(8))) short short8;
typedef __attribute__((ext_vector_type(4))) float f32x4;

constexpr int Bz = 4, SQv = 1024, SKVv = 1024, Dv = 1024, Hv = 16, HDv = 64;
constexpr float SCALEv = 0.125f;  // 1/sqrt(64)

// workspace offsets (bytes)
constexpr size_t OFF_QB  = 0;          // query bf16   [4096][1024]
constexpr size_t OFF_KVB = 8388608;    // key_value bf16
constexpr size_t OFF_WQT = 16777216;   // Wq^T bf16 [1024][1024]
constexpr size_t OFF_WKT = 18874368;
constexpr size_t OFF_WVT = 20971520;
constexpr size_t OFF_WOT = 23068672;
constexpr size_t OFF_REL = 25165824;   // rel bf16 [2048][64] (row 2047 zero pad)
constexpr size_t OFF_Q   = 25427968;   // Q bf16 [4096][1024]
constexpr size_t OFF_K   = 33816576;
constexpr size_t OFF_V   = 42205184;
constexpr size_t OFF_AO  = 50593792;   // attn out bf16 [4096][1024]
// end: 58982400 bytes (~56.3 MB)

__device__ __forceinline__ unsigned short f2bf(float f) {
  union { float f; unsigned int u; } v; v.f = f;
  unsigned int r = (v.u + 0x7fffu + ((v.u >> 16) & 1u)) >> 16;
  return (unsigned short)r;
}

// ---------------- fp32 -> bf16 convert (with optional zero pad tail) -------
__global__ __launch_bounds__(256) void k_cvt(const float* __restrict__ src,
                                             unsigned short* __restrict__ dst,
                                             int n, int nsrc) {
  int i = blockIdx.x * 256 + threadIdx.x;
  if (i < n) dst[i] = (i < nsrc) ? f2bf(src[i]) : (unsigned short)0;
}

// ---------------- W[R][C] fp32 -> Wt[C][R] bf16 ----------------------------
__global__ __launch_bounds__(256) void k_tpose(const float* __restrict__ W,
                                               unsigned short* __restrict__ Wt,
                                               int R, int C) {
  __shared__ unsigned short t[64][72];
  const int r0 = blockIdx.y * 64, c0 = blockIdx.x * 64;
  const int tid = threadIdx.x;
  const int r = tid >> 2, cc = (tid & 3) * 16;
  const float* src = W + (size_t)(r0 + r) * C + c0 + cc;
#pragma unroll
  for (int i = 0; i < 16; i += 4) {
    float4 f = *(const float4*)(src + i);
    t[r][cc + i + 0] = f2bf(f.x);
    t[r][cc + i + 1] = f2bf(f.y);
    t[r][cc + i + 2] = f2bf(f.z);
    t[r][cc + i + 3] = f2bf(f.w);
  }
  __syncthreads();
  unsigned short tmp[16];
#pragma unroll
  for (int i = 0; i < 16; i++) tmp[i] = t[cc + i][r];
  unsigned short* dstp = Wt + (size_t)(c0 + r) * R + r0 + cc;
  *(uint4*)(dstp)     = *(const uint4*)&tmp[0];
  *((uint4*)dstp + 1) = *(const uint4*)&tmp[8];
}

// ---------------- NT GEMM: C[M][N] = A[M][K] @ Bt[N][K]^T + bias -----------
// 128x128 tile, BK=32, 256 thr (4 waves, 2x2 of 64x64), mfma 16x16x32 bf16
template <int OUT_BF16>
__global__ __launch_bounds__(256) void k_gemm(const unsigned short* __restrict__ A,
                                              const unsigned short* __restrict__ Bt,
                                              const float* __restrict__ bias,
                                              void* __restrict__ Cout,
                                              int M, int N, int K) {
  __shared__ unsigned short As[128][32];
  __shared__ unsigned short Bs[128][32];
  const int tid = threadIdx.x;
  const int l = tid & 63, w = tid >> 6;
  const int wr = w >> 1, wc = w & 1;
  const int m0 = blockIdx.y * 128, n0 = blockIdx.x * 128;
  const int sr = tid >> 2;          // 0..63
  const int sk = (tid & 3) * 8;     // 0,8,16,24
  const int lr = l & 15, kk = (l >> 4) * 8;

  f32x4 acc[4][4] = {};

  for (int k0 = 0; k0 < K; k0 += 32) {
    uint4 a0 = *(const uint4*)&A [(size_t)(m0 + sr)      * K + k0 + sk];
    uint4 a1 = *(const uint4*)&A [(size_t)(m0 + 64 + sr) * K + k0 + sk];
    uint4 b0 = *(const uint4*)&Bt[(size_t)(n0 + sr)      * K + k0 + sk];
    uint4 b1 = *(const uint4*)&Bt[(size_t)(n0 + 64 + sr) * K + k0 + sk];
    __syncthreads();  // previous iteration's frag reads done
    *(uint4*)&As[sr][sk]      = a0;
    *(uint4*)&As[sr + 64][sk] = a1;
    *(uint4*)&Bs[sr][sk]      = b0;
    *(uint4*)&Bs[sr + 64][sk] = b1;
    __syncthreads();
    short8 af[4], bf[4];
#pragma unroll
    for (int m = 0; m < 4; m++) af[m] = *(const short8*)&As[wr * 64 + m * 16 + lr][kk];
#pragma unroll
    for (int n = 0; n < 4; n++) bf[n] = *(const short8*)&Bs[wc * 64 + n * 16 + lr][kk];
#pragma unroll
    for (int m = 0; m < 4; m++)
#pragma unroll
      for (int n = 0; n < 4; n++)
        acc[m][n] = __builtin_amdgcn_mfma_f32_16x16x32_bf16(af[m], bf[n], acc[m][n], 0, 0, 0);
  }

#pragma unroll
  for (int m = 0; m < 4; m++) {
    const int row_base = m0 + wr * 64 + m * 16 + (l >> 4) * 4;
#pragma unroll
    for (int n = 0; n < 4; n++) {
      const int col = n0 + wc * 64 + n * 16 + lr;
      const float bv = bias[col];
#pragma unroll
      for (int r = 0; r < 4; r++) {
        const float v = acc[m][n][r] + bv;
        const size_t idx = (size_t)(row_base + r) * N + col;
        if (OUT_BF16) ((unsigned short*)Cout)[idx] = f2bf(v);
        else          ((float*)Cout)[idx] = v;
      }
    }
  }
}

// ---------------- fused attention with relative position bias --------------
// grid (SQ/64, H, B), 256 thr (4 waves). Wave w owns Q rows i0+w*16..+15.
__global__ __launch_bounds__(256) void k_attn(const unsigned short* __restrict__ Qb,
                                              const unsigned short* __restrict__ Kb,
                                              const unsigned short* __restrict__ Vb,
                                              const unsigned short* __restrict__ relb,
                                              unsigned short* __restrict__ AO) {
  __shared__ unsigned short Qs[64][72];
  __shared__ unsigned short Ks[64][72];
  __shared__ unsigned short Vts[64][72];      // transposed: Vts[d][j]
  __shared__ unsigned short Ps[4][16][72];    // per-wave P tile
  __shared__ float Ts[4][16][84];             // per-wave rel band T[i][tb]

  const int tid = threadIdx.x, l = tid & 63, w = tid >> 6;
  const int lr = l & 15, lg = l >> 4, kk = lg * 8;
  const int i0 = blockIdx.x * 64;
  const int h = blockIdx.y;
  const int b = blockIdx.z;

  const unsigned short* Qg = Qb + ((size_t)(b * SQv + i0)) * Dv + h * HDv;
  const unsigned short* Kg = Kb + ((size_t)(b * SKVv)) * Dv + h * HDv;
  const unsigned short* Vg = Vb + ((size_t)(b * SKVv)) * Dv + h * HDv;

  const int sr = tid >> 2, sc = (tid & 3) * 16;

  // stage Q tile once
  {
    uint4 q0 = *(const uint4*)&Qg[(size_t)sr * Dv + sc];
    uint4 q1 = *(const uint4*)&Qg[(size_t)sr * Dv + sc + 8];
    *(uint4*)&Qs[sr][sc]     = q0;
    *(uint4*)&Qs[sr][sc + 8] = q1;
  }
  __syncthreads();

  short8 aq0 = *(const short8*)&Qs[w * 16 + lr][kk];
  short8 aq1 = *(const short8*)&Qs[w * 16 + lr][32 + kk];

  f32x4 Oacc[4] = {};
  float mrow[4], lrow[4];
#pragma unroll
  for (int r = 0; r < 4; r++) { mrow[r] = -1e30f; lrow[r] = 0.f; }

  for (int j0 = 0; j0 < SKVv; j0 += 64) {
    // issue global loads for K/V tile
    uint4 kv0 = *(const uint4*)&Kg[(size_t)(j0 + sr) * Dv + sc];
    uint4 kv1 = *(const uint4*)&Kg[(size_t)(j0 + sr) * Dv + sc + 8];
    union { uint4 u; unsigned short s[8]; } v0, v1;
    v0.u = *(const uint4*)&Vg[(size_t)(j0 + sr) * Dv + sc];
    v1.u = *(const uint4*)&Vg[(size_t)(j0 + sr) * Dv + sc + 8];

    __syncthreads();  // prior iteration's LDS reads complete
    *(uint4*)&Ks[sr][sc]     = kv0;
    *(uint4*)&Ks[sr][sc + 8] = kv1;
#pragma unroll
    for (int i = 0; i < 8; i++) Vts[sc + i][sr] = v0.s[i];
#pragma unroll
    for (int i = 0; i < 8; i++) Vts[sc + 8 + i][sr] = v1.s[i];
    __syncthreads();

    // ---- content scores S = Q K^T (accumulate in fp32) ----
    f32x4 sacc[4] = {};
#pragma unroll
    for (int jf = 0; jf < 4; jf++) {
      short8 bk0 = *(const short8*)&Ks[jf * 16 + lr][kk];
      short8 bk1 = *(const short8*)&Ks[jf * 16 + lr][32 + kk];
      sacc[jf] = __builtin_amdgcn_mfma_f32_16x16x32_bf16(aq0, bk0, sacc[jf], 0, 0, 0);
      sacc[jf] = __builtin_amdgcn_mfma_f32_16x16x32_bf16(aq1, bk1, sacc[jf], 0, 0, 0);
    }

    // ---- rel band: T[rr][tb] = Q[rr] . rel[base + w*16 + tb], tb in [0,80) ----
    const int base = i0 - j0 + 960 + w * 16;
#pragma unroll
    for (int tf = 0; tf < 5; tf++) {
      const unsigned short* rp = &relb[(size_t)(base + tf * 16 + lr) * HDv + kk];
      short8 br0 = *(const short8*)rp;
      short8 br1 = *(const short8*)(rp + 32);
      f32x4 tacc = {};
      tacc = __builtin_amdgcn_mfma_f32_16x16x32_bf16(aq0, br0, tacc, 0, 0, 0);
      tacc = __builtin_amdgcn_mfma_f32_16x16x32_bf16(aq1, br1, tacc, 0, 0, 0);
#pragma unroll
      for (int r = 0; r < 4; r++) Ts[w][lg * 4 + r][tf * 16 + lr] = tacc[r];
    }
    __syncthreads();  // T visible

    // ---- combine + online softmax (rows rr = lg*4+r, cols jj = jf*16+lr) ----
    float p[4][4];
    float rmax[4];
#pragma unroll
    for (int r = 0; r < 4; r++) {
      const int rr = lg * 4 + r;
#pragma unroll
      for (int jf = 0; jf < 4; jf++) {
        const int jj = jf * 16 + lr;
        p[jf][r] = sacc[jf][r] * SCALEv + Ts[w][rr][rr - jj + 63];
      }
      float mx = fmaxf(fmaxf(p[0][r], p[1][r]), fmaxf(p[2][r], p[3][r]));
#pragma unroll
      for (int msk = 1; msk < 16; msk <<= 1) mx = fmaxf(mx, __shfl_xor(mx, msk));
      rmax[r] = mx;
    }
#pragma unroll
    for (int r = 0; r < 4; r++) {
      const float mnew = fmaxf(mrow[r], rmax[r]);
      const float resc = __expf(mrow[r] - mnew);
      mrow[r] = mnew;
      float s = 0.f;
#pragma unroll
      for (int jf = 0; jf < 4; jf++) {
        p[jf][r] = __expf(p[jf][r] - mnew);
        s += p[jf][r];
      }
#pragma unroll
      for (int msk = 1; msk < 16; msk <<= 1) s += __shfl_xor(s, msk);
      lrow[r] = lrow[r] * resc + s;
#pragma unroll
      for (int df = 0; df < 4; df++) Oacc[df][r] *= resc;
      const int rr = lg * 4 + r;
#pragma unroll
      for (int jf = 0; jf < 4; jf++) Ps[w][rr][jf * 16 + lr] = f2bf(p[jf][r]);
    }
    __syncthreads();  // P visible

    // ---- O += P V ----
    short8 ap0 = *(const short8*)&Ps[w][lr][kk];
    short8 ap1 = *(const short8*)&Ps[w][lr][32 + kk];
#pragma unroll
    for (int df = 0; df < 4; df++) {
      short8 bv0 = *(const short8*)&Vts[df * 16 + lr][kk];
      short8 bv1 = *(const short8*)&Vts[df * 16 + lr][32 + kk];
      Oacc[df] = __builtin_amdgcn_mfma_f32_16x16x32_bf16(ap0, bv0, Oacc[df], 0, 0, 0);
      Oacc[df] = __builtin_amdgcn_mfma_f32_16x16x32_bf16(ap1, bv1, Oacc[df], 0, 0, 0);
    }
  }

  // ---- normalize + write attn output (bf16, [B*SQ][D] layout) ----
#pragma unroll
  for (int r = 0; r < 4; r++) {
    const float inv = 1.f / lrow[r];
    const size_t row = (size_t)(b * SQv + i0 + w * 16 + lg * 4 + r) * Dv + h * HDv;
#pragma unroll
    for (int df = 0; df < 4; df++)
      AO[row + df * 16 + lr] = f2bf(Oacc[df][r] * inv);
  }
}

// ---------------------------------------------------------------------------
extern "C" void kernel_launch(void* const* d_in, const int* in_sizes, int n_in,
                              void* d_out, int out_size, void* d_ws, size_t ws_size,
                              hipStream_t stream) {
  const float* query = (const float*)d_in[0];
  const float* keyv  = (const float*)d_in[1];
  const float* Wq    = (const float*)d_in[2];
  const float* bq    = (const float*)d_in[3];
  const float* Wk    = (const float*)d_in[4];
  const float* bk    = (const float*)d_in[5];
  const float* Wv    = (const float*)d_in[6];
  const float* bv    = (const float*)d_in[7];
  const float* Wo    = (const float*)d_in[8];
  const float* bo    = (const float*)d_in[9];
  const float* rel   = (const float*)d_in[10];

  char* ws = (char*)d_ws;
  unsigned short* qb   = (unsigned short*)(ws + OFF_QB);
  unsigned short* kvb  = (unsigned short*)(ws + OFF_KVB);
  unsigned short* Wqt  = (unsigned short*)(ws + OFF_WQT);
  unsigned short* Wkt  = (unsigned short*)(ws + OFF_WKT);
  unsigned short* Wvt  = (unsigned short*)(ws + OFF_WVT);
  unsigned short* Wot  = (unsigned short*)(ws + OFF_WOT);
  unsigned short* relb = (unsigned short*)(ws + OFF_REL);
  unsigned short* Qb   = (unsigned short*)(ws + OFF_Q);
  unsigned short* Kb   = (unsigned short*)(ws + OFF_K);
  unsigned short* Vb   = (unsigned short*)(ws + OFF_V);
  unsigned short* AOb  = (unsigned short*)(ws + OFF_AO);

  const int NE = Bz * SQv * Dv;  // 4194304

  k_cvt<<<NE / 256, 256, 0, stream>>>(query, qb, NE, NE);
  k_cvt<<<NE / 256, 256, 0, stream>>>(keyv, kvb, NE, NE);
  k_cvt<<<512, 256, 0, stream>>>(rel, relb, 2048 * 64, 2047 * 64);

  dim3 tg(16, 16);
  k_tpose<<<tg, 256, 0, stream>>>(Wq, Wqt, Dv, Dv);
  k_tpose<<<tg, 256, 0, stream>>>(Wk, Wkt, Dv, Dv);
  k_tpose<<<tg, 256, 0, stream>>>(Wv, Wvt, Dv, Dv);
  k_tpose<<<tg, 256, 0, stream>>>(Wo, Wot, Dv, Dv);

  dim3 gg(Dv / 128, (Bz * SQv) / 128);  // (8, 32)
  k_gemm<1><<<gg, 256, 0, stream>>>(qb,  Wqt, bq, Qb, Bz * SQv, Dv, Dv);
  k_gemm<1><<<gg, 256, 0, stream>>>(kvb, Wkt, bk, Kb, Bz * SQv, Dv, Dv);
  k_gemm<1><<<gg, 256, 0, stream>>>(kvb, Wvt, bv, Vb, Bz * SQv, Dv, Dv);

  dim3 ga(SQv / 64, Hv, Bz);  // (16, 16, 4)
  k_attn<<<ga, 256, 0, stream>>>(Qb, Kb, Vb, relb, AOb);

  k_gemm<0><<<gg, 256, 0, stream>>>(AOb, Wot, bo, d_out, Bz * SQv, Dv, Dv);
}

// Round 2
// 235.879 us; speedup vs baseline: 1.1104x; 1.1104x over previous
//
#include <hip/hip_runtime.h>
#include <hip/hip_bf16.h>
#include <stdint.h>

// ---------------------------------------------------------------------------
// RelativeCrossAttention: B=4, SQ=SKV=1024, D=1024, H=16, HD=64, MAXL=1024
// Round 2: attn restructure (1 barrier/tile, V pre-transposed, per-wave
// Ts/Ps without barriers, T14 async staging, setprio) + m97-style GEMM
// (global_load_lds width-16 staging).
// ---------------------------------------------------------------------------

typedef __attribute__((ext_vector_type(8))) short short8;
typedef __attribute__((ext_vector_type(4))) float f32x4;

constexpr int Bz = 4, SQv = 1024, SKVv = 1024, Dv = 1024, Hv = 16, HDv = 64;
constexpr float SCALEv = 0.125f;  // 1/sqrt(64)

// workspace offsets (bytes)
constexpr size_t OFF_QB  = 0;          // query bf16   [4096][1024]
constexpr size_t OFF_KVB = 8388608;    // key_value bf16
constexpr size_t OFF_WQT = 16777216;   // Wq^T bf16 [1024][1024]
constexpr size_t OFF_WKT = 18874368;
constexpr size_t OFF_WVT = 20971520;
constexpr size_t OFF_WOT = 23068672;
constexpr size_t OFF_REL = 25165824;   // rel bf16 [2048][64] (row 2047 zero pad)
constexpr size_t OFF_Q   = 25427968;   // Q bf16 [4096][1024]
constexpr size_t OFF_K   = 33816576;   // K bf16 [4096][1024]
constexpr size_t OFF_V   = 42205184;   // V^T bf16 [(b*16+h)*64+d][1024]
constexpr size_t OFF_AO  = 50593792;   // attn out bf16 [4096][1024]

__device__ __forceinline__ unsigned short f2bf(float f) {
  union { float f; unsigned int u; } v; v.f = f;
  unsigned int r = (v.u + 0x7fffu + ((v.u >> 16) & 1u)) >> 16;
  return (unsigned short)r;
}

__device__ __forceinline__ void gload_lds16(const unsigned short* g, unsigned short* l) {
  __builtin_amdgcn_global_load_lds(
      (const __attribute__((address_space(1))) unsigned int*)g,
      (__attribute__((address_space(3))) unsigned int*)l, 16, 0, 0);
}

// ---------------- fp32 -> bf16 convert, 2 tensors fused --------------------
__global__ __launch_bounds__(256) void k_cvt2(const float* __restrict__ s0,
                                              const float* __restrict__ s1,
                                              unsigned short* __restrict__ d0,
                                              unsigned short* __restrict__ d1) {
  int i = blockIdx.x * 256 + threadIdx.x;
  const float* s = blockIdx.y ? s1 : s0;
  unsigned short* d = blockIdx.y ? d1 : d0;
  d[i] = f2bf(s[i]);
}

__global__ __launch_bounds__(256) void k_cvt(const float* __restrict__ src,
                                             unsigned short* __restrict__ dst,
                                             int n, int nsrc) {
  int i = blockIdx.x * 256 + threadIdx.x;
  if (i < n) dst[i] = (i < nsrc) ? f2bf(src[i]) : (unsigned short)0;
}

// ---------------- W[R][C] fp32 -> Wt[C][R] bf16, 4 weights fused -----------
struct TP4 { const float* W[4]; unsigned short* Wt[4]; };
__global__ __launch_bounds__(256) void k_tpose(TP4 p, int R, int C) {
  __shared__ unsigned short t[64][72];
  const float* W = p.W[blockIdx.z];
  unsigned short* Wt = p.Wt[blockIdx.z];
  const int r0 = blockIdx.y * 64, c0 = blockIdx.x * 64;
  const int tid = threadIdx.x;
  const int r = tid >> 2, cc = (tid & 3) * 16;
  const float* src = W + (size_t)(r0 + r) * C + c0 + cc;
#pragma unroll
  for (int i = 0; i < 16; i += 4) {
    float4 f = *(const float4*)(src + i);
    t[r][cc + i + 0] = f2bf(f.x);
    t[r][cc + i + 1] = f2bf(f.y);
    t[r][cc + i + 2] = f2bf(f.z);
    t[r][cc + i + 3] = f2bf(f.w);
  }
  __syncthreads();
  unsigned short tmp[16];
#pragma unroll
  for (int i = 0; i < 16; i++) tmp[i] = t[cc + i][r];
  unsigned short* dstp = Wt + (size_t)(c0 + r) * R + r0 + cc;
  *(uint4*)(dstp)     = *(const uint4*)&tmp[0];
  *((uint4*)dstp + 1) = *(const uint4*)&tmp[8];
}

// ---------------- NT GEMM: C[M][N] = A[M][K] @ Bt[N][K]^T + bias -----------
// 128x128 tile, BK=32, global_load_lds staging (m97 structure).
// OUTMODE: 0 = f32, 1 = bf16, 2 = bf16 per-head transposed (V^T layout)
template <int OUTMODE>
__global__ __launch_bounds__(256) void k_gemm(const unsigned short* __restrict__ A,
                                              const unsigned short* __restrict__ Bt,
                                              const float* __restrict__ bias,
                                              void* __restrict__ Cout,
                                              int M, int N, int K) {
  __shared__ unsigned short As[128 * 32];
  __shared__ unsigned short Bs[128 * 32];
  const int tid = threadIdx.x;
  const int l = tid & 63, w = tid >> 6;
  const int wr = w >> 1, wc = w & 1;
  const int m0 = blockIdx.y * 128, n0 = blockIdx.x * 128;
  const int lr = l & 15, kk = (l >> 4) * 8;
  const int srow = tid >> 2, soff = (tid & 3) * 8;

  const unsigned short* Ag = A + (size_t)(m0 + srow) * K + soff;
  const unsigned short* Bg = Bt + (size_t)(n0 + srow) * K + soff;
  unsigned short* AsD = &As[tid * 8];
  unsigned short* BsD = &Bs[tid * 8];

  f32x4 acc[4][4] = {};

  for (int k0 = 0; k0 < K; k0 += 32) {
    __syncthreads();  // prior frag reads done
    gload_lds16(Ag + k0, AsD);
    gload_lds16(Ag + (size_t)64 * K + k0, AsD + 2048);
    gload_lds16(Bg + k0, BsD);
    gload_lds16(Bg + (size_t)64 * K + k0, BsD + 2048);
    __syncthreads();  // vmcnt(0) drain -> LDS ready
    short8 af[4], bf[4];
#pragma unroll
    for (int m = 0; m < 4; m++) af[m] = *(const short8*)&As[(wr * 64 + m * 16 + lr) * 32 + kk];
#pragma unroll
    for (int n = 0; n < 4; n++) bf[n] = *(const short8*)&Bs[(wc * 64 + n * 16 + lr) * 32 + kk];
    __builtin_amdgcn_s_setprio(1);
#pragma unroll
    for (int m = 0; m < 4; m++)
#pragma unroll
      for (int n = 0; n < 4; n++)
        acc[m][n] = __builtin_amdgcn_mfma_f32_16x16x32_bf16(af[m], bf[n], acc[m][n], 0, 0, 0);
    __builtin_amdgcn_s_setprio(0);
  }

#pragma unroll
  for (int m = 0; m < 4; m++) {
    const int row_base = m0 + wr * 64 + m * 16 + (l >> 4) * 4;
#pragma unroll
    for (int n = 0; n < 4; n++) {
      const int col = n0 + wc * 64 + n * 16 + lr;
      const float bv = bias[col];
      if (OUTMODE == 2) {
        const int h = col >> 6, hd = col & 63;
        const int bb = row_base >> 10, j = row_base & 1023;
        unsigned short t4[4];
#pragma unroll
        for (int r = 0; r < 4; r++) t4[r] = f2bf(acc[m][n][r] + bv);
        *(uint2*)&((unsigned short*)Cout)[((size_t)((bb * 16 + h) * 64 + hd)) * 1024 + j] =
            *(const uint2*)t4;
      } else {
#pragma unroll
        for (int r = 0; r < 4; r++) {
          const float v = acc[m][n][r] + bv;
          const size_t idx = (size_t)(row_base + r) * N + col;
          if (OUTMODE == 1) ((unsigned short*)Cout)[idx] = f2bf(v);
          else              ((float*)Cout)[idx] = v;
        }
      }
    }
  }
}

// ---------------- fused attention with relative position bias --------------
// grid (SQ/64, H, B), 256 thr (4 waves). Wave w owns Q rows i0+w*16..+15.
// One barrier per j-tile; K/V double-buffered; Ts/Ps per-wave (no barrier).
__global__ __launch_bounds__(256) void k_attn(const unsigned short* __restrict__ Qb,
                                              const unsigned short* __restrict__ Kb,
                                              const unsigned short* __restrict__ Vt,
                                              const unsigned short* __restrict__ relb,
                                              unsigned short* __restrict__ AO) {
  __shared__ unsigned short Ks[2][64][68];
  __shared__ unsigned short Vs[2][64][68];
  __shared__ float Ts[4][16][82];
  __shared__ unsigned short Ps[4][16][68];

  const int tid = threadIdx.x, l = tid & 63, w = tid >> 6;
  const int lr = l & 15, lg = l >> 4, kk = lg * 8;
  const int i0 = blockIdx.x * 64;
  const int h = blockIdx.y;
  const int b = blockIdx.z;

  const unsigned short* Kg  = Kb + (size_t)b * SKVv * Dv + h * HDv;
  const unsigned short* Vtg = Vt + ((size_t)(b * Hv + h) * HDv) * (size_t)SKVv;

  // Q fragments straight from global (one-time)
  const unsigned short* Qg = Qb + ((size_t)(b * SQv + i0 + w * 16 + lr)) * Dv + h * HDv;
  short8 aq0 = *(const short8*)&Qg[kk];
  short8 aq1 = *(const short8*)&Qg[32 + kk];

  // staging coords: thread t covers K row j0+sr / Vt row d=sr, 32B chunk sc
  const int sr = tid >> 2, sc = (tid & 3) * 16;

  uint4 pk0, pk1, pv0, pv1;
  auto ldnext = [&](int j0) {
    pk0 = *(const uint4*)&Kg[(size_t)(j0 + sr) * Dv + sc];
    pk1 = *(const uint4*)&Kg[(size_t)(j0 + sr) * Dv + sc + 8];
    pv0 = *(const uint4*)&Vtg[(size_t)sr * SKVv + j0 + sc];
    pv1 = *(const uint4*)&Vtg[(size_t)sr * SKVv + j0 + sc + 8];
  };
  auto wrbuf = [&](int buf) {
    *(uint4*)&Ks[buf][sr][sc]     = pk0;
    *(uint4*)&Ks[buf][sr][sc + 8] = pk1;
    *(uint4*)&Vs[buf][sr][sc]     = pv0;
    *(uint4*)&Vs[buf][sr][sc + 8] = pv1;
  };

  ldnext(0);
  wrbuf(0);
  __syncthreads();

  f32x4 Oacc[4] = {};
  float mrow[4], lrow[4];
#pragma unroll
  for (int r = 0; r < 4; r++) { mrow[r] = -1e30f; lrow[r] = 0.f; }

  for (int it = 0; it < 16; ++it) {
    const int cur = it & 1;
    const int j0 = it * 64;
    if (it < 15) ldnext(j0 + 64);  // T14: issue early, write late

    // ---- content scores S = Q K^T ----
    __builtin_amdgcn_s_setprio(1);
    f32x4 sacc[4] = {};
#pragma unroll
    for (int jf = 0; jf < 4; jf++) {
      short8 bk0 = *(const short8*)&Ks[cur][jf * 16 + lr][kk];
      short8 bk1 = *(const short8*)&Ks[cur][jf * 16 + lr][32 + kk];
      sacc[jf] = __builtin_amdgcn_mfma_f32_16x16x32_bf16(aq0, bk0, sacc[jf], 0, 0, 0);
      sacc[jf] = __builtin_amdgcn_mfma_f32_16x16x32_bf16(aq1, bk1, sacc[jf], 0, 0, 0);
    }

    // ---- rel band: T[rr][tb] = Q[rr] . rel[base + tb], tb in [0,80) ----
    const int base = i0 - j0 + 960 + w * 16;
#pragma unroll
    for (int tf = 0; tf < 5; tf++) {
      const unsigned short* rp = &relb[(size_t)(base + tf * 16 + lr) * HDv];
      short8 br0 = *(const short8*)&rp[kk];
      short8 br1 = *(const short8*)&rp[32 + kk];
      f32x4 tacc = {};
      tacc = __builtin_amdgcn_mfma_f32_16x16x32_bf16(aq0, br0, tacc, 0, 0, 0);
      tacc = __builtin_amdgcn_mfma_f32_16x16x32_bf16(aq1, br1, tacc, 0, 0, 0);
#pragma unroll
      for (int r = 0; r < 4; r++) Ts[w][lg * 4 + r][tf * 16 + lr] = tacc[r];
    }
    __builtin_amdgcn_s_setprio(0);

    // ---- combine + online softmax ----
    float p[4][4];
#pragma unroll
    for (int r = 0; r < 4; r++) {
      const int rr = lg * 4 + r;
#pragma unroll
      for (int jf = 0; jf < 4; jf++) {
        const int jj = jf * 16 + lr;
        p[jf][r] = sacc[jf][r] * SCALEv + Ts[w][rr][rr - jj + 63];
      }
      float mx = fmaxf(fmaxf(p[0][r], p[1][r]), fmaxf(p[2][r], p[3][r]));
#pragma unroll
      for (int msk = 1; msk < 16; msk <<= 1) mx = fmaxf(mx, __shfl_xor(mx, msk));
      const float mnew = fmaxf(mrow[r], mx);
      const float resc = __expf(mrow[r] - mnew);
      mrow[r] = mnew;
      float s = 0.f;
#pragma unroll
      for (int jf = 0; jf < 4; jf++) {
        p[jf][r] = __expf(p[jf][r] - mnew);
        s += p[jf][r];
      }
#pragma unroll
      for (int msk = 1; msk < 16; msk <<= 1) s += __shfl_xor(s, msk);
      lrow[r] = lrow[r] * resc + s;
#pragma unroll
      for (int df = 0; df < 4; df++) Oacc[df][r] *= resc;
#pragma unroll
      for (int jf = 0; jf < 4; jf++) Ps[w][rr][jf * 16 + lr] = f2bf(p[jf][r]);
    }

    // ---- O += P V ----
    short8 ap0 = *(const short8*)&Ps[w][lr][kk];
    short8 ap1 = *(const short8*)&Ps[w][lr][32 + kk];
    __builtin_amdgcn_s_setprio(1);
#pragma unroll
    for (int df = 0; df < 4; df++) {
      short8 bv0 = *(const short8*)&Vs[cur][df * 16 + lr][kk];
      short8 bv1 = *(const short8*)&Vs[cur][df * 16 + lr][32 + kk];
      Oacc[df] = __builtin_amdgcn_mfma_f32_16x16x32_bf16(ap0, bv0, Oacc[df], 0, 0, 0);
      Oacc[df] = __builtin_amdgcn_mfma_f32_16x16x32_bf16(ap1, bv1, Oacc[df], 0, 0, 0);
    }
    __builtin_amdgcn_s_setprio(0);

    if (it < 15) wrbuf(cur ^ 1);  // write-late half of T14 split
    __syncthreads();
  }

  // ---- normalize + write attn output (bf16, [B*SQ][D] layout) ----
#pragma unroll
  for (int r = 0; r < 4; r++) {
    const float inv = 1.f / lrow[r];
    const size_t row = (size_t)(b * SQv + i0 + w * 16 + lg * 4 + r) * Dv + h * HDv;
#pragma unroll
    for (int df = 0; df < 4; df++)
      AO[row + df * 16 + lr] = f2bf(Oacc[df][r] * inv);
  }
}

// ---------------------------------------------------------------------------
extern "C" void kernel_launch(void* const* d_in, const int* in_sizes, int n_in,
                              void* d_out, int out_size, void* d_ws, size_t ws_size,
                              hipStream_t stream) {
  const float* query = (const float*)d_in[0];
  const float* keyv  = (const float*)d_in[1];
  const float* Wq    = (const float*)d_in[2];
  const float* bq    = (const float*)d_in[3];
  const float* Wk    = (const float*)d_in[4];
  const float* bk    = (const float*)d_in[5];
  const float* Wv    = (const float*)d_in[6];
  const float* bv    = (const float*)d_in[7];
  const float* Wo    = (const float*)d_in[8];
  const float* bo    = (const float*)d_in[9];
  const float* rel   = (const float*)d_in[10];

  char* ws = (char*)d_ws;
  unsigned short* qb   = (unsigned short*)(ws + OFF_QB);
  unsigned short* kvb  = (unsigned short*)(ws + OFF_KVB);
  unsigned short* Wqt  = (unsigned short*)(ws + OFF_WQT);
  unsigned short* Wkt  = (unsigned short*)(ws + OFF_WKT);
  unsigned short* Wvt  = (unsigned short*)(ws + OFF_WVT);
  unsigned short* Wot  = (unsigned short*)(ws + OFF_WOT);
  unsigned short* relb = (unsigned short*)(ws + OFF_REL);
  unsigned short* Qb   = (unsigned short*)(ws + OFF_Q);
  unsigned short* Kb   = (unsigned short*)(ws + OFF_K);
  unsigned short* Vtb  = (unsigned short*)(ws + OFF_V);
  unsigned short* AOb  = (unsigned short*)(ws + OFF_AO);

  const int NE = Bz * SQv * Dv;  // 4194304

  dim3 gc(NE / 256, 2);
  k_cvt2<<<gc, 256, 0, stream>>>(query, keyv, qb, kvb);
  k_cvt<<<512, 256, 0, stream>>>(rel, relb, 2048 * 64, 2047 * 64);

  TP4 tp;
  tp.W[0] = Wq;  tp.Wt[0] = Wqt;
  tp.W[1] = Wk;  tp.Wt[1] = Wkt;
  tp.W[2] = Wv;  tp.Wt[2] = Wvt;
  tp.W[3] = Wo;  tp.Wt[3] = Wot;
  dim3 tg(16, 16, 4);
  k_tpose<<<tg, 256, 0, stream>>>(tp, Dv, Dv);

  dim3 gg(Dv / 128, (Bz * SQv) / 128);  // (8, 32)
  k_gemm<1><<<gg, 256, 0, stream>>>(qb,  Wqt, bq, Qb, Bz * SQv, Dv, Dv);
  k_gemm<1><<<gg, 256, 0, stream>>>(kvb, Wkt, bk, Kb, Bz * SQv, Dv, Dv);
  k_gemm<2><<<gg, 256, 0, stream>>>(kvb, Wvt, bv, Vtb, Bz * SQv, Dv, Dv);

  dim3 ga(SQv / 64, Hv, Bz);  // (16, 16, 4)
  k_attn<<<ga, 256, 0, stream>>>(Qb, Kb, Vtb, relb, AOb);

  k_gemm<0><<<gg, 256, 0, stream>>>(AOb, Wot, bo, d_out, Bz * SQv, Dv, Dv);
}

// Round 3
// 184.749 us; speedup vs baseline: 1.4177x; 1.2768x over previous
//
#include <hip/hip_runtime.h>
#include <hip/hip_bf16.h>
#include <stdint.h>

// ---------------------------------------------------------------------------
// RelativeCrossAttention: B=4, SQ=SKV=1024, D=1024, H=16, HD=64, MAXL=1024
// Round 3: fused prep (1 kernel), merged QKV GEMM (z=3, 768 blocks), BM=64
// O-GEMM (512 blocks), attn with pre-shifted Ts (aligned reads), DPP
// rotate-reduce softmax (no ds_swizzle), hoisted rel-band loads.
// ---------------------------------------------------------------------------

typedef __attribute__((ext_vector_type(8))) short short8;
typedef __attribute__((ext_vector_type(4))) float f32x4;

constexpr int Bz = 4, SQv = 1024, SKVv = 1024, Dv = 1024, Hv = 16, HDv = 64;
constexpr float SCALEv = 0.125f;  // 1/sqrt(64)

// workspace offsets (bytes)
constexpr size_t OFF_QB  = 0;          // query bf16   [4096][1024]
constexpr size_t OFF_KVB = 8388608;    // key_value bf16
constexpr size_t OFF_WQT = 16777216;   // Wq^T bf16 [1024][1024]
constexpr size_t OFF_WKT = 18874368;
constexpr size_t OFF_WVT = 20971520;
constexpr size_t OFF_WOT = 23068672;
constexpr size_t OFF_REL = 25165824;   // rel bf16 [2048][64] (row 2047 zero pad)
constexpr size_t OFF_Q   = 25427968;   // Q bf16 [4096][1024]
constexpr size_t OFF_K   = 33816576;   // K bf16 [4096][1024]
constexpr size_t OFF_V   = 42205184;   // V^T bf16 [(b*16+h)*64+d][1024]
constexpr size_t OFF_AO  = 50593792;   // attn out bf16 [4096][1024]

__device__ __forceinline__ unsigned short f2bf(float f) {
  union { float f; unsigned int u; } v; v.f = f;
  unsigned int r = (v.u + 0x7fffu + ((v.u >> 16) & 1u)) >> 16;
  return (unsigned short)r;
}

__device__ __forceinline__ void gload_lds16(const unsigned short* g, unsigned short* l) {
  __builtin_amdgcn_global_load_lds(
      (const __attribute__((address_space(1))) unsigned int*)g,
      (__attribute__((address_space(3))) unsigned int*)l, 16, 0, 0);
}

// DPP row-rotate reduce over 16-lane rows (rotate-reduce == full reduce for
// commutative ops: after ror 1,2,4,8 every lane holds the 16-lane result).
template <int CTRL>
__device__ __forceinline__ float dpp_ror(float v) {
  int x = __builtin_amdgcn_update_dpp(__builtin_bit_cast(int, v),
                                      __builtin_bit_cast(int, v),
                                      CTRL, 0xf, 0xf, false);
  return __builtin_bit_cast(float, x);
}
__device__ __forceinline__ float red16_max(float v) {
  v = fmaxf(v, dpp_ror<0x121>(v));
  v = fmaxf(v, dpp_ror<0x122>(v));
  v = fmaxf(v, dpp_ror<0x124>(v));
  v = fmaxf(v, dpp_ror<0x128>(v));
  return v;
}
__device__ __forceinline__ float red16_sum(float v) {
  v += dpp_ror<0x121>(v);
  v += dpp_ror<0x122>(v);
  v += dpp_ror<0x124>(v);
  v += dpp_ror<0x128>(v);
  return v;
}

// ---------------- fused prep: cvt q/kv/rel + transpose 4 weights -----------
// grid: [0,2048) q cvt | [2048,4096) kv cvt | [4096,4160) rel | [4160,5184) tpose
__global__ __launch_bounds__(256) void k_prep(const float* __restrict__ q,
                                              const float* __restrict__ kv,
                                              const float* __restrict__ rel,
                                              const float* __restrict__ Wq,
                                              const float* __restrict__ Wk,
                                              const float* __restrict__ Wv,
                                              const float* __restrict__ Wo,
                                              unsigned short* __restrict__ qb,
                                              unsigned short* __restrict__ kvb,
                                              unsigned short* __restrict__ relb,
                                              unsigned short* __restrict__ Wqt,
                                              unsigned short* __restrict__ Wkt,
                                              unsigned short* __restrict__ Wvt,
                                              unsigned short* __restrict__ Wot) {
  __shared__ unsigned short t[64][72];
  const int bx = blockIdx.x;
  if (bx < 4096) {
    const float* s = bx < 2048 ? q : kv;
    unsigned short* d = bx < 2048 ? qb : kvb;
    const int base = (bx & 2047) * 2048 + threadIdx.x * 8;
    float4 f0 = *(const float4*)(s + base);
    float4 f1 = *(const float4*)(s + base + 4);
    unsigned short o[8] = {f2bf(f0.x), f2bf(f0.y), f2bf(f0.z), f2bf(f0.w),
                           f2bf(f1.x), f2bf(f1.y), f2bf(f1.z), f2bf(f1.w)};
    *(uint4*)(d + base) = *(const uint4*)o;
    return;
  }
  if (bx < 4160) {
    const int i = (bx - 4096) * 2048 + threadIdx.x * 8;
    const int nsrc = 2047 * 64;
    unsigned short o[8];
    if (i + 8 <= nsrc) {
      float4 f0 = *(const float4*)(rel + i);
      float4 f1 = *(const float4*)(rel + i + 4);
      o[0]=f2bf(f0.x); o[1]=f2bf(f0.y); o[2]=f2bf(f0.z); o[3]=f2bf(f0.w);
      o[4]=f2bf(f1.x); o[5]=f2bf(f1.y); o[6]=f2bf(f1.z); o[7]=f2bf(f1.w);
    } else {
#pragma unroll
      for (int k = 0; k < 8; k++) o[k] = (i + k < nsrc) ? f2bf(rel[i + k]) : (unsigned short)0;
    }
    *(uint4*)(relb + i) = *(const uint4*)o;
    return;
  }
  // weight transpose
  const int tt = bx - 4160;
  const int z = tt >> 8, tile = tt & 255;
  const float* W = z == 0 ? Wq : z == 1 ? Wk : z == 2 ? Wv : Wo;
  unsigned short* Wt = z == 0 ? Wqt : z == 1 ? Wkt : z == 2 ? Wvt : Wot;
  const int r0 = (tile >> 4) * 64, c0 = (tile & 15) * 64;
  const int tid = threadIdx.x;
  const int r = tid >> 2, cc = (tid & 3) * 16;
  const float* src = W + (size_t)(r0 + r) * Dv + c0 + cc;
#pragma unroll
  for (int i = 0; i < 16; i += 4) {
    float4 f = *(const float4*)(src + i);
    t[r][cc + i + 0] = f2bf(f.x);
    t[r][cc + i + 1] = f2bf(f.y);
    t[r][cc + i + 2] = f2bf(f.z);
    t[r][cc + i + 3] = f2bf(f.w);
  }
  __syncthreads();
  unsigned short tmp[16];
#pragma unroll
  for (int i = 0; i < 16; i++) tmp[i] = t[cc + i][r];
  unsigned short* dstp = Wt + (size_t)(c0 + r) * Dv + r0 + cc;
  *(uint4*)(dstp)     = *(const uint4*)&tmp[0];
  *((uint4*)dstp + 1) = *(const uint4*)&tmp[8];
}

// ---------------- merged QKV NT GEMM (z = 0,1,2), 128x128 tile -------------
__global__ __launch_bounds__(256) void k_gemm3(const unsigned short* __restrict__ qb,
                                               const unsigned short* __restrict__ kvb,
                                               const unsigned short* __restrict__ Wqt,
                                               const unsigned short* __restrict__ Wkt,
                                               const unsigned short* __restrict__ Wvt,
                                               const float* __restrict__ bq,
                                               const float* __restrict__ bk,
                                               const float* __restrict__ bv,
                                               unsigned short* __restrict__ Qb,
                                               unsigned short* __restrict__ Kb,
                                               unsigned short* __restrict__ Vtb) {
  __shared__ unsigned short As[128 * 32];
  __shared__ unsigned short Bs[128 * 32];
  const int z = blockIdx.z;
  const unsigned short* A  = z == 0 ? qb : kvb;
  const unsigned short* Bt = z == 0 ? Wqt : z == 1 ? Wkt : Wvt;
  const float* bias        = z == 0 ? bq : z == 1 ? bk : bv;
  unsigned short* Cout     = z == 0 ? Qb : z == 1 ? Kb : Vtb;
  const int K = Dv, N = Dv;

  const int tid = threadIdx.x;
  const int l = tid & 63, w = tid >> 6;
  const int wr = w >> 1, wc = w & 1;
  const int m0 = blockIdx.y * 128, n0 = blockIdx.x * 128;
  const int lr = l & 15, kk = (l >> 4) * 8;
  const int srow = tid >> 2, soff = (tid & 3) * 8;

  const unsigned short* Ag = A + (size_t)(m0 + srow) * K + soff;
  const unsigned short* Bg = Bt + (size_t)(n0 + srow) * K + soff;
  unsigned short* AsD = &As[tid * 8];
  unsigned short* BsD = &Bs[tid * 8];

  f32x4 acc[4][4] = {};

  for (int k0 = 0; k0 < K; k0 += 32) {
    __syncthreads();
    gload_lds16(Ag + k0, AsD);
    gload_lds16(Ag + (size_t)64 * K + k0, AsD + 2048);
    gload_lds16(Bg + k0, BsD);
    gload_lds16(Bg + (size_t)64 * K + k0, BsD + 2048);
    __syncthreads();
    short8 af[4], bf[4];
#pragma unroll
    for (int m = 0; m < 4; m++) af[m] = *(const short8*)&As[(wr * 64 + m * 16 + lr) * 32 + kk];
#pragma unroll
    for (int n = 0; n < 4; n++) bf[n] = *(const short8*)&Bs[(wc * 64 + n * 16 + lr) * 32 + kk];
    __builtin_amdgcn_s_setprio(1);
#pragma unroll
    for (int m = 0; m < 4; m++)
#pragma unroll
      for (int n = 0; n < 4; n++)
        acc[m][n] = __builtin_amdgcn_mfma_f32_16x16x32_bf16(af[m], bf[n], acc[m][n], 0, 0, 0);
    __builtin_amdgcn_s_setprio(0);
  }

#pragma unroll
  for (int m = 0; m < 4; m++) {
    const int row_base = m0 + wr * 64 + m * 16 + (l >> 4) * 4;
#pragma unroll
    for (int n = 0; n < 4; n++) {
      const int col = n0 + wc * 64 + n * 16 + lr;
      const float bv4 = bias[col];
      if (z == 2) {
        // V^T layout: [(b*16+h)*64+hd][j]
        const int h = col >> 6, hd = col & 63;
        const int bb = row_base >> 10, j = row_base & 1023;
        unsigned short t4[4];
#pragma unroll
        for (int r = 0; r < 4; r++) t4[r] = f2bf(acc[m][n][r] + bv4);
        *(uint2*)&Cout[((size_t)((bb * 16 + h) * 64 + hd)) * 1024 + j] = *(const uint2*)t4;
      } else {
#pragma unroll
        for (int r = 0; r < 4; r++)
          Cout[(size_t)(row_base + r) * N + col] = f2bf(acc[m][n][r] + bv4);
      }
    }
  }
}

// ---------------- O-proj NT GEMM: 64x128 tile, fp32 out --------------------
__global__ __launch_bounds__(256) void k_gemmO(const unsigned short* __restrict__ A,
                                               const unsigned short* __restrict__ Bt,
                                               const float* __restrict__ bias,
                                               float* __restrict__ Cout) {
  __shared__ unsigned short As[64 * 32];
  __shared__ unsigned short Bs[128 * 32];
  const int K = Dv, N = Dv;
  const int tid = threadIdx.x;
  const int l = tid & 63, w = tid >> 6;
  const int wr = w >> 1, wc = w & 1;
  const int m0 = blockIdx.y * 64, n0 = blockIdx.x * 128;
  const int lr = l & 15, kk = (l >> 4) * 8;
  const int srow = tid >> 2, soff = (tid & 3) * 8;

  const unsigned short* Ag = A + (size_t)(m0 + srow) * K + soff;
  const unsigned short* Bg = Bt + (size_t)(n0 + srow) * K + soff;
  unsigned short* AsD = &As[tid * 8];
  unsigned short* BsD = &Bs[tid * 8];

  f32x4 acc[2][4] = {};

  for (int k0 = 0; k0 < K; k0 += 32) {
    __syncthreads();
    gload_lds16(Ag + k0, AsD);
    gload_lds16(Bg + k0, BsD);
    gload_lds16(Bg + (size_t)64 * K + k0, BsD + 2048);
    __syncthreads();
    short8 af[2], bf[4];
#pragma unroll
    for (int m = 0; m < 2; m++) af[m] = *(const short8*)&As[(wr * 32 + m * 16 + lr) * 32 + kk];
#pragma unroll
    for (int n = 0; n < 4; n++) bf[n] = *(const short8*)&Bs[(wc * 64 + n * 16 + lr) * 32 + kk];
    __builtin_amdgcn_s_setprio(1);
#pragma unroll
    for (int m = 0; m < 2; m++)
#pragma unroll
      for (int n = 0; n < 4; n++)
        acc[m][n] = __builtin_amdgcn_mfma_f32_16x16x32_bf16(af[m], bf[n], acc[m][n], 0, 0, 0);
    __builtin_amdgcn_s_setprio(0);
  }

#pragma unroll
  for (int m = 0; m < 2; m++) {
    const int row_base = m0 + wr * 32 + m * 16 + (l >> 4) * 4;
#pragma unroll
    for (int n = 0; n < 4; n++) {
      const int col = n0 + wc * 64 + n * 16 + lr;
      const float bv4 = bias[col];
#pragma unroll
      for (int r = 0; r < 4; r++)
        Cout[(size_t)(row_base + r) * N + col] = acc[m][n][r] + bv4;
    }
  }
}

// ---------------- fused attention with relative position bias --------------
// grid (SQ/64, H, B), 256 thr (4 waves). Wave w owns Q rows i0+w*16..+15.
__global__ __launch_bounds__(256) void k_attn(const unsigned short* __restrict__ Qb,
                                              const unsigned short* __restrict__ Kb,
                                              const unsigned short* __restrict__ Vt,
                                              const unsigned short* __restrict__ relb,
                                              unsigned short* __restrict__ AO) {
  __shared__ unsigned short Ks[2][64][68];
  __shared__ unsigned short Vs[2][64][68];
  __shared__ float Ts[4][16][66];            // pre-shifted: col = rr - tb + 63
  __shared__ unsigned short Ps[4][16][68];

  const int tid = threadIdx.x, l = tid & 63, w = tid >> 6;
  const int lr = l & 15, lg = l >> 4, kk = lg * 8;
  const int i0 = blockIdx.x * 64;
  const int h = blockIdx.y;
  const int b = blockIdx.z;

  const unsigned short* Kg  = Kb + (size_t)b * SKVv * Dv + h * HDv;
  const unsigned short* Vtg = Vt + ((size_t)(b * Hv + h) * HDv) * (size_t)SKVv;

  // Q fragments straight from global (one-time)
  const unsigned short* Qg = Qb + ((size_t)(b * SQv + i0 + w * 16 + lr)) * Dv + h * HDv;
  short8 aq0 = *(const short8*)&Qg[kk];
  short8 aq1 = *(const short8*)&Qg[32 + kk];

  const int sr = tid >> 2, sc = (tid & 3) * 16;

  uint4 pk0, pk1, pv0, pv1;
  auto ldnext = [&](int j0) {
    pk0 = *(const uint4*)&Kg[(size_t)(j0 + sr) * Dv + sc];
    pk1 = *(const uint4*)&Kg[(size_t)(j0 + sr) * Dv + sc + 8];
    pv0 = *(const uint4*)&Vtg[(size_t)sr * SKVv + j0 + sc];
    pv1 = *(const uint4*)&Vtg[(size_t)sr * SKVv + j0 + sc + 8];
  };
  auto wrbuf = [&](int buf) {
    *(uint4*)&Ks[buf][sr][sc]     = pk0;
    *(uint4*)&Ks[buf][sr][sc + 8] = pk1;
    *(uint4*)&Vs[buf][sr][sc]     = pv0;
    *(uint4*)&Vs[buf][sr][sc + 8] = pv1;
  };

  ldnext(0);
  wrbuf(0);
  __syncthreads();

  f32x4 Oacc[4] = {};
  float mrow[4], lrow[4];
#pragma unroll
  for (int r = 0; r < 4; r++) { mrow[r] = -1e30f; lrow[r] = 0.f; }

  for (int it = 0; it < 16; ++it) {
    const int cur = it & 1;
    const int j0 = it * 64;
    if (it < 15) ldnext(j0 + 64);  // T14: issue early, write late

    // hoist rel-band fragment loads (L2-resident; hide under QK MFMAs)
    const int base = i0 - j0 + 960 + w * 16;
    short8 br0[5], br1[5];
#pragma unroll
    for (int tf = 0; tf < 5; tf++) {
      const unsigned short* rp = &relb[(size_t)(base + tf * 16 + lr) * HDv];
      br0[tf] = *(const short8*)&rp[kk];
      br1[tf] = *(const short8*)&rp[32 + kk];
    }

    // ---- content scores S = Q K^T ----
    __builtin_amdgcn_s_setprio(1);
    f32x4 sacc[4] = {};
#pragma unroll
    for (int jf = 0; jf < 4; jf++) {
      short8 bk0 = *(const short8*)&Ks[cur][jf * 16 + lr][kk];
      short8 bk1 = *(const short8*)&Ks[cur][jf * 16 + lr][32 + kk];
      sacc[jf] = __builtin_amdgcn_mfma_f32_16x16x32_bf16(aq0, bk0, sacc[jf], 0, 0, 0);
      sacc[jf] = __builtin_amdgcn_mfma_f32_16x16x32_bf16(aq1, bk1, sacc[jf], 0, 0, 0);
    }

    // ---- rel band T, stored pre-shifted: Ts[w][rr][rr - tb + 63] ----
#pragma unroll
    for (int tf = 0; tf < 5; tf++) {
      f32x4 tacc = {};
      tacc = __builtin_amdgcn_mfma_f32_16x16x32_bf16(aq0, br0[tf], tacc, 0, 0, 0);
      tacc = __builtin_amdgcn_mfma_f32_16x16x32_bf16(aq1, br1[tf], tacc, 0, 0, 0);
#pragma unroll
      for (int r = 0; r < 4; r++) {
        const int col = (lg * 4 + r) - (tf * 16 + lr) + 63;
        if ((unsigned)col < 64u) Ts[w][lg * 4 + r][col] = tacc[r];
      }
    }
    __builtin_amdgcn_s_setprio(0);

    // ---- combine + online softmax (aligned Ts reads, DPP reduces) ----
    float p[4][4];
#pragma unroll
    for (int r = 0; r < 4; r++) {
      const int rr = lg * 4 + r;
#pragma unroll
      for (int jf = 0; jf < 4; jf++)
        p[jf][r] = sacc[jf][r] * SCALEv + Ts[w][rr][jf * 16 + lr];
      float mx = fmaxf(fmaxf(p[0][r], p[1][r]), fmaxf(p[2][r], p[3][r]));
      mx = red16_max(mx);
      const float mnew = fmaxf(mrow[r], mx);
      const float resc = __expf(mrow[r] - mnew);
      mrow[r] = mnew;
      float s = 0.f;
#pragma unroll
      for (int jf = 0; jf < 4; jf++) {
        p[jf][r] = __expf(p[jf][r] - mnew);
        s += p[jf][r];
      }
      s = red16_sum(s);
      lrow[r] = lrow[r] * resc + s;
#pragma unroll
      for (int df = 0; df < 4; df++) Oacc[df][r] *= resc;
#pragma unroll
      for (int jf = 0; jf < 4; jf++) Ps[w][rr][jf * 16 + lr] = f2bf(p[jf][r]);
    }

    // ---- O += P V ----
    short8 ap0 = *(const short8*)&Ps[w][lr][kk];
    short8 ap1 = *(const short8*)&Ps[w][lr][32 + kk];
    __builtin_amdgcn_s_setprio(1);
#pragma unroll
    for (int df = 0; df < 4; df++) {
      short8 bv0 = *(const short8*)&Vs[cur][df * 16 + lr][kk];
      short8 bv1 = *(const short8*)&Vs[cur][df * 16 + lr][32 + kk];
      Oacc[df] = __builtin_amdgcn_mfma_f32_16x16x32_bf16(ap0, bv0, Oacc[df], 0, 0, 0);
      Oacc[df] = __builtin_amdgcn_mfma_f32_16x16x32_bf16(ap1, bv1, Oacc[df], 0, 0, 0);
    }
    __builtin_amdgcn_s_setprio(0);

    if (it < 15) wrbuf(cur ^ 1);
    __syncthreads();
  }

  // ---- normalize + write attn output (bf16, [B*SQ][D] layout) ----
#pragma unroll
  for (int r = 0; r < 4; r++) {
    const float inv = 1.f / lrow[r];
    const size_t row = (size_t)(b * SQv + i0 + w * 16 + lg * 4 + r) * Dv + h * HDv;
#pragma unroll
    for (int df = 0; df < 4; df++)
      AO[row + df * 16 + lr] = f2bf(Oacc[df][r] * inv);
  }
}

// ---------------------------------------------------------------------------
extern "C" void kernel_launch(void* const* d_in, const int* in_sizes, int n_in,
                              void* d_out, int out_size, void* d_ws, size_t ws_size,
                              hipStream_t stream) {
  const float* query = (const float*)d_in[0];
  const float* keyv  = (const float*)d_in[1];
  const float* Wq    = (const float*)d_in[2];
  const float* bq    = (const float*)d_in[3];
  const float* Wk    = (const float*)d_in[4];
  const float* bk    = (const float*)d_in[5];
  const float* Wv    = (const float*)d_in[6];
  const float* bv    = (const float*)d_in[7];
  const float* Wo    = (const float*)d_in[8];
  const float* bo    = (const float*)d_in[9];
  const float* rel   = (const float*)d_in[10];

  char* ws = (char*)d_ws;
  unsigned short* qb   = (unsigned short*)(ws + OFF_QB);
  unsigned short* kvb  = (unsigned short*)(ws + OFF_KVB);
  unsigned short* Wqt  = (unsigned short*)(ws + OFF_WQT);
  unsigned short* Wkt  = (unsigned short*)(ws + OFF_WKT);
  unsigned short* Wvt  = (unsigned short*)(ws + OFF_WVT);
  unsigned short* Wot  = (unsigned short*)(ws + OFF_WOT);
  unsigned short* relb = (unsigned short*)(ws + OFF_REL);
  unsigned short* Qb   = (unsigned short*)(ws + OFF_Q);
  unsigned short* Kb   = (unsigned short*)(ws + OFF_K);
  unsigned short* Vtb  = (unsigned short*)(ws + OFF_V);
  unsigned short* AOb  = (unsigned short*)(ws + OFF_AO);

  k_prep<<<5184, 256, 0, stream>>>(query, keyv, rel, Wq, Wk, Wv, Wo,
                                   qb, kvb, relb, Wqt, Wkt, Wvt, Wot);

  dim3 g3(Dv / 128, (Bz * SQv) / 128, 3);  // (8, 32, 3) = 768 blocks
  k_gemm3<<<g3, 256, 0, stream>>>(qb, kvb, Wqt, Wkt, Wvt, bq, bk, bv, Qb, Kb, Vtb);

  dim3 ga(SQv / 64, Hv, Bz);  // (16, 16, 4)
  k_attn<<<ga, 256, 0, stream>>>(Qb, Kb, Vtb, relb, AOb);

  dim3 go(Dv / 128, (Bz * SQv) / 64);  // (8, 64) = 512 blocks
  k_gemmO<<<go, 256, 0, stream>>>(AOb, Wot, bo, (float*)d_out);
}